// Round 12
// baseline (251.935 us; speedup 1.0000x reference)
//
#include <hip/hip_runtime.h>

#ifndef __has_builtin
#define __has_builtin(x) 0
#endif

#define NOBS_OS 8
#define NOBS_TS 6
#define HID 128
#define NACT 9
#define BTOT 32768
#define NTS 32
#define ROWS 16        // batch rows per tile
#define NTILES 2048    // 2048*16 = 32768
#define QUADS 512      // one block per quad of adjacent sorted tiles
#define BLOCK 512      // 8 waves; wave w owns hidden cols [16w,16w+16)
#define PREB 128       // pre-pass blocks (256 thr each)

// workspace layout (int32 offsets)
#define LEN_OFF 0
#define PERM_OFF BTOT
#define HIST_OFF (2 * BTOT)   // PREB x 33 per-block histograms

typedef __attribute__((ext_vector_type(8))) short short8;
typedef __attribute__((ext_vector_type(4))) float f32x4;

__device__ inline unsigned short f2bf(float x) {
  unsigned int u = __float_as_uint(x);
  u += 0x7FFFu + ((u >> 16) & 1u);
  return (unsigned short)(u >> 16);
}

// packed f32x2 -> bf16x2 (low = a, high = b)
__device__ inline unsigned pkbf(float a, float b) {
#if __has_builtin(__builtin_amdgcn_cvt_pk_bf16_f32)
  auto v = __builtin_amdgcn_cvt_pk_bf16_f32(a, b);
  unsigned u;
  __builtin_memcpy(&u, &v, sizeof(u));
  return u;
#else
  return ((unsigned)f2bf(b) << 16) | (unsigned)f2bf(a);
#endif
}

__device__ inline float fexp2(float x) {
#if __has_builtin(__builtin_amdgcn_exp2f)
  return __builtin_amdgcn_exp2f(x);
#else
  return exp2f(x);
#endif
}
__device__ inline float frcp_(float x) {
#if __has_builtin(__builtin_amdgcn_rcpf)
  return __builtin_amdgcn_rcpf(x);
#else
  return 1.0f / x;
#endif
}

__device__ inline short8 pack8(f32x4 a, f32x4 b) {
  union { unsigned u[4]; short8 s; } r;
  r.u[0] = pkbf(a[0], a[1]); r.u[1] = pkbf(a[2], a[3]);
  r.u[2] = pkbf(b[0], b[1]); r.u[3] = pkbf(b[2], b[3]);
  return r.s;
}

__device__ inline short8 pack8s(const float* p, float s) {
  union { unsigned u[4]; short8 r; } r;
#pragma unroll
  for (int i = 0; i < 4; ++i) r.u[i] = pkbf(p[2 * i] * s, p[2 * i + 1] * s);
  return r.r;
}

// ---- fused counting-sort pre-pass (2 kernels, no global atomics) --------
__global__ void count_kernel(const float* __restrict__ s, int* __restrict__ ws) {
  __shared__ int lh[NTS + 1];
  const int tid = threadIdx.x;
  if (tid <= NTS) lh[tid] = 0;
  __syncthreads();
  const int row = blockIdx.x * 256 + tid;
  const float* p = s + (size_t)row * 200 + NOBS_OS;
  int lo = 0, hi = NTS;
  while (lo < hi) {
    const int mid = (lo + hi) >> 1;
    const float v = p[mid * NOBS_TS];
    if (v == v) lo = mid + 1; else hi = mid;
  }
  ws[LEN_OFF + row] = lo;
  atomicAdd(&lh[lo], 1);
  __syncthreads();
  if (tid <= NTS) ws[HIST_OFF + blockIdx.x * (NTS + 1) + tid] = lh[tid];
}

__global__ void scatter_kernel(int* __restrict__ ws) {
  __shared__ int tot[NTS + 1], pre[NTS + 1], gb[NTS + 1], lh[NTS + 1];
  const int tid = threadIdx.x;
  if (tid <= NTS) {
    int t = 0, pr = 0;
    for (int k = 0; k < PREB; ++k) {
      const int h = ws[HIST_OFF + k * (NTS + 1) + tid];
      t += h;
      if (k < (int)blockIdx.x) pr += h;
    }
    tot[tid] = t;
    pre[tid] = pr;
    lh[tid] = 0;
  }
  __syncthreads();
  if (tid == 0) {
    int a = 0;
    for (int b = 0; b <= NTS; ++b) { gb[b] = a; a += tot[b]; }
  }
  __syncthreads();
  const int row = blockIdx.x * 256 + tid;
  const int len = ws[LEN_OFF + row];
  const int r = atomicAdd(&lh[len], 1);
  __syncthreads();
  ws[PERM_OFF + gb[len] + pre[len] + r] = row;
}

// ---- main fused kernel: quad-chain interleave, register capture ----------
// A-frag layout in LDS (16 rows x K): elem idx = kt*512 + lane*8 + jj
// C-layout writes at column k: idx = (k>>5)*512 + ((k>>3)&3)*128 + m*8 + (k&7)
// Weights prescaled: i,f,o by -1/log2(e), g by -2/log2(e); fused products:
//   i*g = (1-eg)*rcp((1+ei)(1+eg)); f*c = c*rcp(1+ef);
//   o*tanh(c) = (1-ec)*rcp((1+eo)(1+ec)), ec = exp2(-2c*log2e)
// Bias rides as the C operand of the x-gate MFMA (no acc-init movs).
// x_TS capture is register-based (cndmask on packed tcap byte), written to
// xtsb once after the loop. Chain index CN must be a literal.

#define GATES_X(CN, T)                                                       \
  f32x4 acc[4];                                                              \
  {                                                                          \
    short8 ax = z8;                                                          \
    if (q == 0) ax = *(const short8*)&x_st[CN][c * 264 + (T) * 8];           \
    _Pragma("unroll") for (int a = 0; a < 4; ++a)                            \
        acc[a] = __builtin_amdgcn_mfma_f32_16x16x32_bf16(ax, Bh[a][4],       \
                                                         biasv[a], 0, 0, 0); \
  }

#define GATES_H(CN, T)                                                       \
  {                                                                          \
    const unsigned short* hb = hA[CN][((T) + 1) & 1];                        \
    _Pragma("unroll") for (int kt = 0; kt < 4; ++kt) {                       \
      const short8 ah = *(const short8*)&hb[kt * 512 + L * 8];               \
      _Pragma("unroll") for (int a = 0; a < 4; ++a)                          \
          acc[a] = __builtin_amdgcn_mfma_f32_16x16x32_bf16(ah, Bh[a][kt],    \
                                                           acc[a], 0, 0, 0); \
    }                                                                        \
  }

#define ACT_STORE(CN, T)                                                     \
  {                                                                          \
    unsigned short* hw = &hA[CN][(T) & 1][pbase];                            \
    float hv[4];                                                             \
    _Pragma("unroll") for (int r = 0; r < 4; ++r) {                          \
      const float ei = fexp2(acc[0][r]);                                     \
      const float ef = fexp2(acc[1][r]);                                     \
      const float eg = fexp2(acc[2][r]);                                     \
      const float eo = fexp2(acc[3][r]);                                     \
      const float rig = frcp_((1.0f + ei) * (1.0f + eg));                    \
      const float rf = frcp_(1.0f + ef);                                     \
      const float cv = cc[CN][r] * rf + (1.0f - eg) * rig;                   \
      cc[CN][r] = cv;                                                        \
      const float ec = fexp2(cv * -2.88539008f);                             \
      const float roc = frcp_((1.0f + eo) * (1.0f + ec));                    \
      hv[r] = (1.0f - ec) * roc;                                             \
    }                                                                        \
    const unsigned p01 = pkbf(hv[0], hv[1]);                                 \
    const unsigned p23 = pkbf(hv[2], hv[3]);                                 \
    hw[0] = (unsigned short)p01;                                             \
    hw[8] = (unsigned short)(p01 >> 16);                                     \
    hw[16] = (unsigned short)p23;                                            \
    hw[24] = (unsigned short)(p23 >> 16);                                    \
    _Pragma("unroll") for (int r = 0; r < 4; ++r) {                          \
      if (((tpck[CN] >> (r * 8)) & 255u) == (unsigned)(T))                   \
        xts[CN][r] = hv[r];                                                  \
    }                                                                        \
  }

#define STEP_FULL(CN, T) { GATES_X(CN, T) GATES_H(CN, T) ACT_STORE(CN, T) }
#define STEP_X(CN) { GATES_X(CN, 0) ACT_STORE(CN, 0) }

__global__ __launch_bounds__(BLOCK, 2) void recdqn_kernel(
    const float* __restrict__ s, const float* __restrict__ W_os,
    const float* __restrict__ b_os, const float* __restrict__ W_ih,
    const float* __restrict__ W_hh, const float* __restrict__ b_ih,
    const float* __restrict__ b_hh, const float* __restrict__ W_ts,
    const float* __restrict__ b_ts, const float* __restrict__ W_c1,
    const float* __restrict__ b_c1, const float* __restrict__ W_c2,
    const float* __restrict__ b_c2, const int* __restrict__ ws,
    float* __restrict__ out) {
  __shared__ unsigned short x_st[4][ROWS * 264]; // [chain][row][t][8] bf16
  __shared__ unsigned short hA[4][2][2048];      // [chain][buf] h A-frag
  __shared__ unsigned short xtsb[4][2048];       // captured h at t=len-1
  __shared__ unsigned short xcat[4096];          // concat A-frag (K=256), shared
  __shared__ unsigned short x2b[2048];           // W_c1 out A-frag, shared
  __shared__ int n_lds[4][ROWS];
  __shared__ int rid_s[4][ROWS];
  __shared__ int tmax_sh[4];

  const int tid = threadIdx.x;
  const int L = tid & 63;
  const int w = tid >> 6;   // wave 0..7: hidden cols [16w, 16w+16)
  const int c = L & 15;
  const int q = L >> 4;
  const int j = (w << 4) | c;

  const short8 z8 = {0, 0, 0, 0, 0, 0, 0, 0};

  // ---- one-time: prescaled W_hh/W_ih B-fragments + bias vectors
  short8 Bh[4][5];
  f32x4 biasv[4];
#pragma unroll
  for (int a = 0; a < 4; ++a) {
    const float sc = (a == 2) ? -2.88539008f : -1.44269504f;
    const int n = (a << 7) + j;
    const float bb = sc * (b_ih[n] + b_hh[n]);
    f32x4 bv = {bb, bb, bb, bb};
    biasv[a] = bv;
#pragma unroll
    for (int kt = 0; kt < 4; ++kt)
      Bh[a][kt] = pack8s(W_hh + n * HID + kt * 32 + q * 8, sc);
    short8 fx = z8;
    if (q == 0) {
      const float* px = W_ih + n * NOBS_TS;
      union { unsigned u[4]; short8 s; } fu;
      fu.u[0] = pkbf(px[0] * sc, px[1] * sc);
      fu.u[1] = pkbf(px[2] * sc, px[3] * sc);
      fu.u[2] = pkbf(px[4] * sc, px[5] * sc);
      fu.u[3] = 0;
      fx = fu.s;
    }
    Bh[a][4] = fx;
  }

  const int pbase = ((j >> 5) << 9) + (((j >> 3) & 3) << 7) + (q << 5) + (j & 7);

  // ---- pick tile quad: adjacent sorted tiles, longest-first (LPT)
  const int p = (QUADS - 1) - blockIdx.x;
  if (tid < 64) {
    const int cn = tid >> 4, rr = tid & 15;
    const int row = ws[PERM_OFF + (4 * p + cn) * ROWS + rr];
    rid_s[cn][rr] = row;
    n_lds[cn][rr] = ws[LEN_OFF + row];
  }
  __syncthreads();

  // ---- stage s_TS -> LDS bf16 for all 4 chains (zeros past length)
#pragma unroll
  for (int it = 0; it < 4; ++it) {
    const int slot = tid + it * 512;
    const int cn = slot >> 9, rt = slot & 511, r = rt >> 5, tq = rt & 31;
    short8 v = z8;
    if (tq < n_lds[cn][r]) {
      const float2* ps =
          (const float2*)(s + (size_t)rid_s[cn][r] * 200 + NOBS_OS + tq * NOBS_TS);
      const float2 A = ps[0], Bv = ps[1], Cv = ps[2];
      union { unsigned u[4]; short8 s; } vu;
      vu.u[0] = pkbf(A.x, A.y);
      vu.u[1] = pkbf(Bv.x, Bv.y);
      vu.u[2] = pkbf(Cv.x, Cv.y);
      vu.u[3] = 0;
      v = vu.s;
    }
    *(short8*)&x_st[cn][r * 264 + tq * 8] = v;
  }
  if (tid == 0) {
#pragma unroll
    for (int cn = 0; cn < 4; ++cn) {
      int mx = 0;
      for (int r = 0; r < ROWS; ++r) mx = max(mx, n_lds[cn][r]);
      tmax_sh[cn] = mx;
    }
  }
  __syncthreads();

  const int tm0 = tmax_sh[0], tm1 = tmax_sh[1];
  const int tm2 = tmax_sh[2], tm3 = tmax_sh[3]; // ascending (sorted)
  unsigned tpck[4];
#pragma unroll
  for (int cn = 0; cn < 4; ++cn) {
    unsigned pk = 0;
#pragma unroll
    for (int b = 0; b < 4; ++b)
      pk |= ((unsigned)((n_lds[cn][q * 4 + b] - 1) & 255)) << (b * 8);
    tpck[cn] = pk;
  }

  float cc[4][4], xts[4][4];
#pragma unroll
  for (int i = 0; i < 4; ++i) {
    cc[0][i] = 0.0f; cc[1][i] = 0.0f; cc[2][i] = 0.0f; cc[3][i] = 0.0f;
    xts[0][i] = 0.0f; xts[1][i] = 0.0f; xts[2][i] = 0.0f; xts[3][i] = 0.0f;
  }

  // ---- interleaved quad-chain LSTM time loop (register capture)
  if (tm3 > 0) {
    if (tm0 > 0) STEP_X(0)
    if (tm1 > 0) STEP_X(1)
    if (tm2 > 0) STEP_X(2)
    STEP_X(3)
    __syncthreads();
    int t = 1;
    for (; t < tm0; ++t) {
      STEP_FULL(0, t)
      STEP_FULL(1, t)
      STEP_FULL(2, t)
      STEP_FULL(3, t)
      __syncthreads();
    }
    for (; t < tm1; ++t) {
      STEP_FULL(1, t)
      STEP_FULL(2, t)
      STEP_FULL(3, t)
      __syncthreads();
    }
    for (; t < tm2; ++t) {
      STEP_FULL(2, t)
      STEP_FULL(3, t)
      __syncthreads();
    }
    for (; t < tm3; ++t) {
      STEP_FULL(3, t)
      __syncthreads();
    }
  }

  // ---- write captured x_TS (registers) -> xtsb in A-frag layout
#pragma unroll
  for (int cn = 0; cn < 4; ++cn) {
    const unsigned p01 = pkbf(xts[cn][0], xts[cn][1]);
    const unsigned p23 = pkbf(xts[cn][2], xts[cn][3]);
    unsigned short* pw = &xtsb[cn][pbase];
    pw[0] = (unsigned short)p01;
    pw[8] = (unsigned short)(p01 >> 16);
    pw[16] = (unsigned short)p23;
    pw[24] = (unsigned short)(p23 >> 16);
  }
  __syncthreads();

  // ---- hoisted head weight fragments (bf16), reused by all chains
  short8 Fts[4], Fc1[8], Fc2[4], bosf = z8;
#pragma unroll
  for (int kt = 0; kt < 4; ++kt) {
    const f32x4* pp = (const f32x4*)(W_ts + j * HID + kt * 32 + q * 8);
    Fts[kt] = pack8(pp[0], pp[1]);
  }
#pragma unroll
  for (int kt = 0; kt < 8; ++kt) {
    const f32x4* pp = (const f32x4*)(W_c1 + j * 256 + kt * 32 + q * 8);
    Fc1[kt] = pack8(pp[0], pp[1]);
  }
#pragma unroll
  for (int kt = 0; kt < 4; ++kt) Fc2[kt] = z8;
  if (w == 0 && c < NACT) {
#pragma unroll
    for (int kt = 0; kt < 4; ++kt) {
      const f32x4* pp = (const f32x4*)(W_c2 + c * HID + kt * 32 + q * 8);
      Fc2[kt] = pack8(pp[0], pp[1]);
    }
  }
  if (q == 0) {
    const f32x4* pb = (const f32x4*)(W_os + j * NOBS_OS);
    bosf = pack8(pb[0], pb[1]);
  }
  const float bts = b_ts[j], bc1 = b_c1[j], bos = b_os[j];
  const float bc2 = (w == 0 && c < NACT) ? b_c2[c] : 0.0f;

  // ---- heads, per chain (shared xcat/x2b)
#pragma unroll 1
  for (int cn = 0; cn < 4; ++cn) {
    // x_TS = relu(xts @ W_ts^T + b_ts) -> xcat k=128+j
    {
      f32x4 a2 = {bts, bts, bts, bts};
#pragma unroll
      for (int kt = 0; kt < 4; ++kt) {
        const short8 af = *(const short8*)&xtsb[cn][kt * 512 + L * 8];
        a2 = __builtin_amdgcn_mfma_f32_16x16x32_bf16(af, Fts[kt], a2, 0, 0, 0);
      }
      const unsigned p01 = pkbf(fmaxf(a2[0], 0.0f), fmaxf(a2[1], 0.0f));
      const unsigned p23 = pkbf(fmaxf(a2[2], 0.0f), fmaxf(a2[3], 0.0f));
      xcat[2048 + pbase + 0] = (unsigned short)p01;
      xcat[2048 + pbase + 8] = (unsigned short)(p01 >> 16);
      xcat[2048 + pbase + 16] = (unsigned short)p23;
      xcat[2048 + pbase + 24] = (unsigned short)(p23 >> 16);
    }
    // x_OS = relu(s_OS @ W_os^T + b_os) -> xcat k=j
    {
      short8 aos = z8;
      if (q == 0) {
        const f32x4* pa = (const f32x4*)(s + (size_t)rid_s[cn][c] * 200);
        aos = pack8(pa[0], pa[1]);
      }
      f32x4 a2 = {bos, bos, bos, bos};
      a2 = __builtin_amdgcn_mfma_f32_16x16x32_bf16(aos, bosf, a2, 0, 0, 0);
      const unsigned p01 = pkbf(fmaxf(a2[0], 0.0f), fmaxf(a2[1], 0.0f));
      const unsigned p23 = pkbf(fmaxf(a2[2], 0.0f), fmaxf(a2[3], 0.0f));
      xcat[pbase + 0] = (unsigned short)p01;
      xcat[pbase + 8] = (unsigned short)(p01 >> 16);
      xcat[pbase + 16] = (unsigned short)p23;
      xcat[pbase + 24] = (unsigned short)(p23 >> 16);
    }
    __syncthreads();
    // x = relu(xcat @ W_c1^T + b_c1) -> x2b (K=256)
    {
      f32x4 a2 = {bc1, bc1, bc1, bc1};
#pragma unroll
      for (int kt = 0; kt < 8; ++kt) {
        const short8 af = *(const short8*)&xcat[kt * 512 + L * 8];
        a2 = __builtin_amdgcn_mfma_f32_16x16x32_bf16(af, Fc1[kt], a2, 0, 0, 0);
      }
      const unsigned p01 = pkbf(fmaxf(a2[0], 0.0f), fmaxf(a2[1], 0.0f));
      const unsigned p23 = pkbf(fmaxf(a2[2], 0.0f), fmaxf(a2[3], 0.0f));
      x2b[pbase + 0] = (unsigned short)p01;
      x2b[pbase + 8] = (unsigned short)(p01 >> 16);
      x2b[pbase + 16] = (unsigned short)p23;
      x2b[pbase + 24] = (unsigned short)(p23 >> 16);
    }
    __syncthreads();
    // out = x2 @ W_c2^T + b_c2 (wave 0; cols c<9 valid)
    if (w == 0) {
      f32x4 accf = {bc2, bc2, bc2, bc2};
#pragma unroll
      for (int kt = 0; kt < 4; ++kt) {
        const short8 af = *(const short8*)&x2b[kt * 512 + L * 8];
        accf = __builtin_amdgcn_mfma_f32_16x16x32_bf16(af, Fc2[kt], accf, 0, 0, 0);
      }
      if (c < NACT) {
#pragma unroll
        for (int r = 0; r < 4; ++r)
          out[(size_t)rid_s[cn][q * 4 + r] * NACT + c] = accf[r];
      }
    }
    __syncthreads(); // protect xcat/x2b reuse by next chain
  }
}

extern "C" void kernel_launch(void* const* d_in, const int* in_sizes, int n_in,
                              void* d_out, int out_size, void* d_ws, size_t ws_size,
                              hipStream_t stream) {
  (void)in_sizes; (void)n_in; (void)out_size; (void)ws_size;
  const float* s    = (const float*)d_in[0];
  const float* W_os = (const float*)d_in[1];
  const float* b_os = (const float*)d_in[2];
  const float* W_ih = (const float*)d_in[3];
  const float* W_hh = (const float*)d_in[4];
  const float* b_ih = (const float*)d_in[5];
  const float* b_hh = (const float*)d_in[6];
  const float* W_ts = (const float*)d_in[7];
  const float* b_ts = (const float*)d_in[8];
  const float* W_c1 = (const float*)d_in[9];
  const float* b_c1 = (const float*)d_in[10];
  const float* W_c2 = (const float*)d_in[11];
  const float* b_c2 = (const float*)d_in[12];
  int* ws = (int*)d_ws;
  float* outp = (float*)d_out;

  count_kernel<<<PREB, 256, 0, stream>>>(s, ws);
  scatter_kernel<<<PREB, 256, 0, stream>>>(ws);
  recdqn_kernel<<<QUADS, BLOCK, 0, stream>>>(
      s, W_os, b_os, W_ih, W_hh, b_ih, b_hh, W_ts, b_ts, W_c1, b_c1, W_c2,
      b_c2, ws, outp);
}

// Round 13
// 244.361 us; speedup vs baseline: 1.0310x; 1.0310x over previous
//
#include <hip/hip_runtime.h>

#ifndef __has_builtin
#define __has_builtin(x) 0
#endif

#define NOBS_OS 8
#define NOBS_TS 6
#define HID 128
#define NACT 9
#define BTOT 32768
#define NTS 32
#define ROWS 16        // batch rows per tile
#define NTILES 2048    // 2048*16 = 32768
#define QUADS 512      // one block per quad of adjacent sorted tiles
#define BLOCK 512      // 8 waves; wave w owns hidden cols [16w,16w+16)
#define PREB 128       // pre-pass blocks (256 thr each)

// workspace layout (int32 offsets)
#define LEN_OFF 0
#define PERM_OFF BTOT
#define HIST_OFF (2 * BTOT)   // PREB x 33 per-block histograms

typedef __attribute__((ext_vector_type(8))) short short8;
typedef __attribute__((ext_vector_type(4))) float f32x4;

__device__ inline unsigned short f2bf(float x) {
  unsigned int u = __float_as_uint(x);
  u += 0x7FFFu + ((u >> 16) & 1u);
  return (unsigned short)(u >> 16);
}

// packed f32x2 -> bf16x2 (low = a, high = b)
__device__ inline unsigned pkbf(float a, float b) {
#if __has_builtin(__builtin_amdgcn_cvt_pk_bf16_f32)
  auto v = __builtin_amdgcn_cvt_pk_bf16_f32(a, b);
  unsigned u;
  __builtin_memcpy(&u, &v, sizeof(u));
  return u;
#else
  return ((unsigned)f2bf(b) << 16) | (unsigned)f2bf(a);
#endif
}

__device__ inline float fexp2(float x) {
#if __has_builtin(__builtin_amdgcn_exp2f)
  return __builtin_amdgcn_exp2f(x);
#else
  return exp2f(x);
#endif
}
__device__ inline float frcp_(float x) {
#if __has_builtin(__builtin_amdgcn_rcpf)
  return __builtin_amdgcn_rcpf(x);
#else
  return 1.0f / x;
#endif
}

__device__ inline short8 pack8(f32x4 a, f32x4 b) {
  union { unsigned u[4]; short8 s; } r;
  r.u[0] = pkbf(a[0], a[1]); r.u[1] = pkbf(a[2], a[3]);
  r.u[2] = pkbf(b[0], b[1]); r.u[3] = pkbf(b[2], b[3]);
  return r.s;
}

__device__ inline short8 pack8s(const float* p, float s) {
  union { unsigned u[4]; short8 r; } r;
#pragma unroll
  for (int i = 0; i < 4; ++i) r.u[i] = pkbf(p[2 * i] * s, p[2 * i + 1] * s);
  return r.r;
}

// ---- fused counting-sort pre-pass (2 kernels, no global atomics) --------
__global__ void count_kernel(const float* __restrict__ s, int* __restrict__ ws) {
  __shared__ int lh[NTS + 1];
  const int tid = threadIdx.x;
  if (tid <= NTS) lh[tid] = 0;
  __syncthreads();
  const int row = blockIdx.x * 256 + tid;
  const float* p = s + (size_t)row * 200 + NOBS_OS;
  int lo = 0, hi = NTS;
  while (lo < hi) {
    const int mid = (lo + hi) >> 1;
    const float v = p[mid * NOBS_TS];
    if (v == v) lo = mid + 1; else hi = mid;
  }
  ws[LEN_OFF + row] = lo;
  atomicAdd(&lh[lo], 1);
  __syncthreads();
  if (tid <= NTS) ws[HIST_OFF + blockIdx.x * (NTS + 1) + tid] = lh[tid];
}

__global__ void scatter_kernel(int* __restrict__ ws) {
  __shared__ int tot[NTS + 1], pre[NTS + 1], gb[NTS + 1], lh[NTS + 1];
  const int tid = threadIdx.x;
  if (tid <= NTS) {
    int t = 0, pr = 0;
    for (int k = 0; k < PREB; ++k) {
      const int h = ws[HIST_OFF + k * (NTS + 1) + tid];
      t += h;
      if (k < (int)blockIdx.x) pr += h;
    }
    tot[tid] = t;
    pre[tid] = pr;
    lh[tid] = 0;
  }
  __syncthreads();
  if (tid == 0) {
    int a = 0;
    for (int b = 0; b <= NTS; ++b) { gb[b] = a; a += tot[b]; }
  }
  __syncthreads();
  const int row = blockIdx.x * 256 + tid;
  const int len = ws[LEN_OFF + row];
  const int r = atomicAdd(&lh[len], 1);
  __syncthreads();
  ws[PERM_OFF + gb[len] + pre[len] + r] = row;
}

// ---- main fused kernel: quad-chain, PHASE-BATCHED steps ------------------
// A-frag layout in LDS (16 rows x K): elem idx = kt*512 + lane*8 + jj
// C-layout writes at column k: idx = (k>>5)*512 + ((k>>3)&3)*128 + m*8 + (k&7)
// Weights prescaled: i,f,o by -1/log2(e), g by -2/log2(e); fused products:
//   i*g = (1-eg)*rcp((1+ei)(1+eg)); f*c = c*rcp(1+ef);
//   o*tanh(c) = (1-ec)*rcp((1+eo)(1+ec)), ec = exp2(-2c*log2e)
// Per quad-step: ALL chains' MFMAs issue first (acc[4][4] live -> cross-chain
// overlap), then ALL chains' activations. Bias rides as the MFMA C operand.
// x_TS capture is register-based. Chain index CN must be a literal.

#define GX(CN, T)                                                            \
  {                                                                          \
    short8 ax = z8;                                                          \
    if (q == 0) ax = *(const short8*)&x_st[CN][c * 264 + (T) * 8];           \
    _Pragma("unroll") for (int a = 0; a < 4; ++a)                            \
        acc[CN][a] = __builtin_amdgcn_mfma_f32_16x16x32_bf16(                \
            ax, Bh[a][4], biasv[a], 0, 0, 0);                                \
  }

#define GH(CN, T)                                                            \
  {                                                                          \
    const unsigned short* hb = hA[CN][((T) + 1) & 1];                        \
    _Pragma("unroll") for (int kt = 0; kt < 4; ++kt) {                       \
      const short8 ah = *(const short8*)&hb[kt * 512 + L * 8];               \
      _Pragma("unroll") for (int a = 0; a < 4; ++a)                          \
          acc[CN][a] = __builtin_amdgcn_mfma_f32_16x16x32_bf16(              \
              ah, Bh[a][kt], acc[CN][a], 0, 0, 0);                           \
    }                                                                        \
  }

#define ACT(CN, T)                                                           \
  {                                                                          \
    unsigned short* hw = &hA[CN][(T) & 1][pbase];                            \
    float hv[4];                                                             \
    _Pragma("unroll") for (int r = 0; r < 4; ++r) {                          \
      const float ei = fexp2(acc[CN][0][r]);                                 \
      const float ef = fexp2(acc[CN][1][r]);                                 \
      const float eg = fexp2(acc[CN][2][r]);                                 \
      const float eo = fexp2(acc[CN][3][r]);                                 \
      const float rig = frcp_((1.0f + ei) * (1.0f + eg));                    \
      const float rf = frcp_(1.0f + ef);                                     \
      const float cv = cc[CN][r] * rf + (1.0f - eg) * rig;                   \
      cc[CN][r] = cv;                                                        \
      const float ec = fexp2(cv * -2.88539008f);                             \
      const float roc = frcp_((1.0f + eo) * (1.0f + ec));                    \
      hv[r] = (1.0f - ec) * roc;                                             \
    }                                                                        \
    const unsigned p01 = pkbf(hv[0], hv[1]);                                 \
    const unsigned p23 = pkbf(hv[2], hv[3]);                                 \
    hw[0] = (unsigned short)p01;                                             \
    hw[8] = (unsigned short)(p01 >> 16);                                     \
    hw[16] = (unsigned short)p23;                                            \
    hw[24] = (unsigned short)(p23 >> 16);                                    \
    _Pragma("unroll") for (int r = 0; r < 4; ++r) {                          \
      if (((tpck[CN] >> (r * 8)) & 255u) == (unsigned)(T))                   \
        xts[CN][r] = hv[r];                                                  \
    }                                                                        \
  }

__global__ __launch_bounds__(BLOCK, 2) void recdqn_kernel(
    const float* __restrict__ s, const float* __restrict__ W_os,
    const float* __restrict__ b_os, const float* __restrict__ W_ih,
    const float* __restrict__ W_hh, const float* __restrict__ b_ih,
    const float* __restrict__ b_hh, const float* __restrict__ W_ts,
    const float* __restrict__ b_ts, const float* __restrict__ W_c1,
    const float* __restrict__ b_c1, const float* __restrict__ W_c2,
    const float* __restrict__ b_c2, const int* __restrict__ ws,
    float* __restrict__ out) {
  __shared__ unsigned short x_st[4][ROWS * 264]; // [chain][row][t][8] bf16
  __shared__ unsigned short hA[4][2][2048];      // [chain][buf] h A-frag
  __shared__ unsigned short xtsb[4][2048];       // captured h at t=len-1
  __shared__ unsigned short xcat[4096];          // concat A-frag (K=256), shared
  __shared__ unsigned short x2b[2048];           // W_c1 out A-frag, shared
  __shared__ int n_lds[4][ROWS];
  __shared__ int rid_s[4][ROWS];
  __shared__ int tmax_sh[4];

  const int tid = threadIdx.x;
  const int L = tid & 63;
  const int w = tid >> 6;   // wave 0..7: hidden cols [16w, 16w+16)
  const int c = L & 15;
  const int q = L >> 4;
  const int j = (w << 4) | c;

  const short8 z8 = {0, 0, 0, 0, 0, 0, 0, 0};

  // ---- one-time: prescaled W_hh/W_ih B-fragments + bias vectors
  short8 Bh[4][5];
  f32x4 biasv[4];
#pragma unroll
  for (int a = 0; a < 4; ++a) {
    const float sc = (a == 2) ? -2.88539008f : -1.44269504f;
    const int n = (a << 7) + j;
    const float bb = sc * (b_ih[n] + b_hh[n]);
    f32x4 bv = {bb, bb, bb, bb};
    biasv[a] = bv;
#pragma unroll
    for (int kt = 0; kt < 4; ++kt)
      Bh[a][kt] = pack8s(W_hh + n * HID + kt * 32 + q * 8, sc);
    short8 fx = z8;
    if (q == 0) {
      const float* px = W_ih + n * NOBS_TS;
      union { unsigned u[4]; short8 s; } fu;
      fu.u[0] = pkbf(px[0] * sc, px[1] * sc);
      fu.u[1] = pkbf(px[2] * sc, px[3] * sc);
      fu.u[2] = pkbf(px[4] * sc, px[5] * sc);
      fu.u[3] = 0;
      fx = fu.s;
    }
    Bh[a][4] = fx;
  }

  const int pbase = ((j >> 5) << 9) + (((j >> 3) & 3) << 7) + (q << 5) + (j & 7);

  // ---- pick tile quad: adjacent sorted tiles, longest-first (LPT)
  const int p = (QUADS - 1) - blockIdx.x;
  if (tid < 64) {
    const int cn = tid >> 4, rr = tid & 15;
    const int row = ws[PERM_OFF + (4 * p + cn) * ROWS + rr];
    rid_s[cn][rr] = row;
    n_lds[cn][rr] = ws[LEN_OFF + row];
  }
  __syncthreads();

  // ---- stage s_TS -> LDS bf16 for all 4 chains (zeros past length)
#pragma unroll
  for (int it = 0; it < 4; ++it) {
    const int slot = tid + it * 512;
    const int cn = slot >> 9, rt = slot & 511, r = rt >> 5, tq = rt & 31;
    short8 v = z8;
    if (tq < n_lds[cn][r]) {
      const float2* ps =
          (const float2*)(s + (size_t)rid_s[cn][r] * 200 + NOBS_OS + tq * NOBS_TS);
      const float2 A = ps[0], Bv = ps[1], Cv = ps[2];
      union { unsigned u[4]; short8 s; } vu;
      vu.u[0] = pkbf(A.x, A.y);
      vu.u[1] = pkbf(Bv.x, Bv.y);
      vu.u[2] = pkbf(Cv.x, Cv.y);
      vu.u[3] = 0;
      v = vu.s;
    }
    *(short8*)&x_st[cn][r * 264 + tq * 8] = v;
  }
  if (tid == 0) {
#pragma unroll
    for (int cn = 0; cn < 4; ++cn) {
      int mx = 0;
      for (int r = 0; r < ROWS; ++r) mx = max(mx, n_lds[cn][r]);
      tmax_sh[cn] = mx;
    }
  }
  __syncthreads();

  const int tm0 = tmax_sh[0], tm1 = tmax_sh[1];
  const int tm2 = tmax_sh[2], tm3 = tmax_sh[3]; // ascending (sorted)
  unsigned tpck[4];
#pragma unroll
  for (int cn = 0; cn < 4; ++cn) {
    unsigned pk = 0;
#pragma unroll
    for (int b = 0; b < 4; ++b)
      pk |= ((unsigned)((n_lds[cn][q * 4 + b] - 1) & 255)) << (b * 8);
    tpck[cn] = pk;
  }

  float cc[4][4], xts[4][4];
#pragma unroll
  for (int i = 0; i < 4; ++i) {
    cc[0][i] = 0.0f; cc[1][i] = 0.0f; cc[2][i] = 0.0f; cc[3][i] = 0.0f;
    xts[0][i] = 0.0f; xts[1][i] = 0.0f; xts[2][i] = 0.0f; xts[3][i] = 0.0f;
  }

  // ---- quad-chain LSTM time loop, phase-batched (MFMAs, then activations)
  f32x4 acc[4][4];
  if (tm3 > 0) {
    if (tm0 > 0) GX(0, 0)
    if (tm1 > 0) GX(1, 0)
    if (tm2 > 0) GX(2, 0)
    GX(3, 0)
    if (tm0 > 0) ACT(0, 0)
    if (tm1 > 0) ACT(1, 0)
    if (tm2 > 0) ACT(2, 0)
    ACT(3, 0)
    __syncthreads();
    int t = 1;
    for (; t < tm0; ++t) {
      GX(0, t) GH(0, t)
      GX(1, t) GH(1, t)
      GX(2, t) GH(2, t)
      GX(3, t) GH(3, t)
      ACT(0, t) ACT(1, t) ACT(2, t) ACT(3, t)
      __syncthreads();
    }
    for (; t < tm1; ++t) {
      GX(1, t) GH(1, t)
      GX(2, t) GH(2, t)
      GX(3, t) GH(3, t)
      ACT(1, t) ACT(2, t) ACT(3, t)
      __syncthreads();
    }
    for (; t < tm2; ++t) {
      GX(2, t) GH(2, t)
      GX(3, t) GH(3, t)
      ACT(2, t) ACT(3, t)
      __syncthreads();
    }
    for (; t < tm3; ++t) {
      GX(3, t) GH(3, t)
      ACT(3, t)
      __syncthreads();
    }
  }

  // ---- write captured x_TS (registers) -> xtsb in A-frag layout
#pragma unroll
  for (int cn = 0; cn < 4; ++cn) {
    const unsigned p01 = pkbf(xts[cn][0], xts[cn][1]);
    const unsigned p23 = pkbf(xts[cn][2], xts[cn][3]);
    unsigned short* pw = &xtsb[cn][pbase];
    pw[0] = (unsigned short)p01;
    pw[8] = (unsigned short)(p01 >> 16);
    pw[16] = (unsigned short)p23;
    pw[24] = (unsigned short)(p23 >> 16);
  }
  __syncthreads();

  // ---- hoisted head weight fragments (bf16), reused by all chains
  short8 Fts[4], Fc1[8], Fc2[4], bosf = z8;
#pragma unroll
  for (int kt = 0; kt < 4; ++kt) {
    const f32x4* pp = (const f32x4*)(W_ts + j * HID + kt * 32 + q * 8);
    Fts[kt] = pack8(pp[0], pp[1]);
  }
#pragma unroll
  for (int kt = 0; kt < 8; ++kt) {
    const f32x4* pp = (const f32x4*)(W_c1 + j * 256 + kt * 32 + q * 8);
    Fc1[kt] = pack8(pp[0], pp[1]);
  }
#pragma unroll
  for (int kt = 0; kt < 4; ++kt) Fc2[kt] = z8;
  if (w == 0 && c < NACT) {
#pragma unroll
    for (int kt = 0; kt < 4; ++kt) {
      const f32x4* pp = (const f32x4*)(W_c2 + c * HID + kt * 32 + q * 8);
      Fc2[kt] = pack8(pp[0], pp[1]);
    }
  }
  if (q == 0) {
    const f32x4* pb = (const f32x4*)(W_os + j * NOBS_OS);
    bosf = pack8(pb[0], pb[1]);
  }
  const float bts = b_ts[j], bc1 = b_c1[j], bos = b_os[j];
  const float bc2 = (w == 0 && c < NACT) ? b_c2[c] : 0.0f;

  // ---- heads, per chain (shared xcat/x2b)
#pragma unroll 1
  for (int cn = 0; cn < 4; ++cn) {
    // x_TS = relu(xts @ W_ts^T + b_ts) -> xcat k=128+j
    {
      f32x4 a2 = {bts, bts, bts, bts};
#pragma unroll
      for (int kt = 0; kt < 4; ++kt) {
        const short8 af = *(const short8*)&xtsb[cn][kt * 512 + L * 8];
        a2 = __builtin_amdgcn_mfma_f32_16x16x32_bf16(af, Fts[kt], a2, 0, 0, 0);
      }
      const unsigned p01 = pkbf(fmaxf(a2[0], 0.0f), fmaxf(a2[1], 0.0f));
      const unsigned p23 = pkbf(fmaxf(a2[2], 0.0f), fmaxf(a2[3], 0.0f));
      xcat[2048 + pbase + 0] = (unsigned short)p01;
      xcat[2048 + pbase + 8] = (unsigned short)(p01 >> 16);
      xcat[2048 + pbase + 16] = (unsigned short)p23;
      xcat[2048 + pbase + 24] = (unsigned short)(p23 >> 16);
    }
    // x_OS = relu(s_OS @ W_os^T + b_os) -> xcat k=j
    {
      short8 aos = z8;
      if (q == 0) {
        const f32x4* pa = (const f32x4*)(s + (size_t)rid_s[cn][c] * 200);
        aos = pack8(pa[0], pa[1]);
      }
      f32x4 a2 = {bos, bos, bos, bos};
      a2 = __builtin_amdgcn_mfma_f32_16x16x32_bf16(aos, bosf, a2, 0, 0, 0);
      const unsigned p01 = pkbf(fmaxf(a2[0], 0.0f), fmaxf(a2[1], 0.0f));
      const unsigned p23 = pkbf(fmaxf(a2[2], 0.0f), fmaxf(a2[3], 0.0f));
      xcat[pbase + 0] = (unsigned short)p01;
      xcat[pbase + 8] = (unsigned short)(p01 >> 16);
      xcat[pbase + 16] = (unsigned short)p23;
      xcat[pbase + 24] = (unsigned short)(p23 >> 16);
    }
    __syncthreads();
    // x = relu(xcat @ W_c1^T + b_c1) -> x2b (K=256)
    {
      f32x4 a2 = {bc1, bc1, bc1, bc1};
#pragma unroll
      for (int kt = 0; kt < 8; ++kt) {
        const short8 af = *(const short8*)&xcat[kt * 512 + L * 8];
        a2 = __builtin_amdgcn_mfma_f32_16x16x32_bf16(af, Fc1[kt], a2, 0, 0, 0);
      }
      const unsigned p01 = pkbf(fmaxf(a2[0], 0.0f), fmaxf(a2[1], 0.0f));
      const unsigned p23 = pkbf(fmaxf(a2[2], 0.0f), fmaxf(a2[3], 0.0f));
      x2b[pbase + 0] = (unsigned short)p01;
      x2b[pbase + 8] = (unsigned short)(p01 >> 16);
      x2b[pbase + 16] = (unsigned short)p23;
      x2b[pbase + 24] = (unsigned short)(p23 >> 16);
    }
    __syncthreads();
    // out = x2 @ W_c2^T + b_c2 (wave 0; cols c<9 valid)
    if (w == 0) {
      f32x4 accf = {bc2, bc2, bc2, bc2};
#pragma unroll
      for (int kt = 0; kt < 4; ++kt) {
        const short8 af = *(const short8*)&x2b[kt * 512 + L * 8];
        accf = __builtin_amdgcn_mfma_f32_16x16x32_bf16(af, Fc2[kt], accf, 0, 0, 0);
      }
      if (c < NACT) {
#pragma unroll
        for (int r = 0; r < 4; ++r)
          out[(size_t)rid_s[cn][q * 4 + r] * NACT + c] = accf[r];
      }
    }
    __syncthreads(); // protect xcat/x2b reuse by next chain
  }
}

extern "C" void kernel_launch(void* const* d_in, const int* in_sizes, int n_in,
                              void* d_out, int out_size, void* d_ws, size_t ws_size,
                              hipStream_t stream) {
  (void)in_sizes; (void)n_in; (void)out_size; (void)ws_size;
  const float* s    = (const float*)d_in[0];
  const float* W_os = (const float*)d_in[1];
  const float* b_os = (const float*)d_in[2];
  const float* W_ih = (const float*)d_in[3];
  const float* W_hh = (const float*)d_in[4];
  const float* b_ih = (const float*)d_in[5];
  const float* b_hh = (const float*)d_in[6];
  const float* W_ts = (const float*)d_in[7];
  const float* b_ts = (const float*)d_in[8];
  const float* W_c1 = (const float*)d_in[9];
  const float* b_c1 = (const float*)d_in[10];
  const float* W_c2 = (const float*)d_in[11];
  const float* b_c2 = (const float*)d_in[12];
  int* ws = (int*)d_ws;
  float* outp = (float*)d_out;

  count_kernel<<<PREB, 256, 0, stream>>>(s, ws);
  scatter_kernel<<<PREB, 256, 0, stream>>>(ws);
  recdqn_kernel<<<QUADS, BLOCK, 0, stream>>>(
      s, W_os, b_os, W_ih, W_hh, b_ih, b_hh, W_ts, b_ts, W_c1, b_c1, W_c2,
      b_c2, ws, outp);
}